// Round 18
// baseline (525.014 us; speedup 1.0000x reference)
//
#include <hip/hip_runtime.h>

#define NPTS 32768
#define DIM 32
#define NH 8
#define NC 3
#define BSZ 128
#define NB 256
#define DH 35
#define DP 36
#define NSEG 24   // C*H

typedef unsigned long long ull;
typedef __attribute__((ext_vector_type(8))) short bf16x8;
typedef __attribute__((ext_vector_type(4))) float f32x4;

__device__ __forceinline__ unsigned fmap(float f){
  unsigned b = __float_as_uint(f);
  return (b & 0x80000000u) ? ~b : (b | 0x80000000u);
}
__device__ __forceinline__ float funmap(unsigned u){
  unsigned b = (u & 0x80000000u) ? (u & 0x7fffffffu) : ~u;
  return __uint_as_float(b);
}
__device__ __forceinline__ unsigned short f2bf(float f){
  unsigned u = __float_as_uint(f);
  u += 0x7fffu + ((u >> 16) & 1u);
  return (unsigned short)(u >> 16);
}
__device__ __forceinline__ float bf2f(unsigned short h){
  return __uint_as_float(((unsigned)h) << 16);
}
__device__ __forceinline__ unsigned cvtpk_bf16(float a, float b){
  unsigned r;
  asm("v_cvt_pk_bf16_f32 %0, %1, %2" : "=v"(r) : "v"(a), "v"(b));
  return r;
}

__device__ __forceinline__ void cswap(ull& a, ull& b, bool up){
  if ((a > b) == up){ ull t = a; a = b; b = t; }
}
// bitonic stages k=2,4,8 on 8 contiguous elements starting at gbase (gbase%8==0)
__device__ __forceinline__ void bitonic8_initial(ull r[8], unsigned gbase){
  #pragma unroll
  for (int p = 0; p < 4; ++p){
    bool up = (((gbase + 2*p) & 2) == 0);
    cswap(r[2*p], r[2*p+1], up);
  }
  #pragma unroll
  for (int b = 0; b < 2; ++b){
    bool up = (((gbase + 4*b) & 4) == 0);
    cswap(r[4*b+0], r[4*b+2], up);
    cswap(r[4*b+1], r[4*b+3], up);
    cswap(r[4*b+0], r[4*b+1], up);
    cswap(r[4*b+2], r[4*b+3], up);
  }
  bool up = ((gbase & 8) == 0);
  #pragma unroll
  for (int i = 0; i < 4; ++i) cswap(r[i], r[i+4], up);
  #pragma unroll
  for (int b = 0; b < 2; ++b){
    cswap(r[4*b+0], r[4*b+2], up);
    cswap(r[4*b+1], r[4*b+3], up);
  }
  #pragma unroll
  for (int p = 0; p < 4; ++p) cswap(r[2*p], r[2*p+1], up);
}
// j=4,2,1 finish of a stage k>=16; direction uniform across the 8
__device__ __forceinline__ void bitonic8_finish(ull r[8], bool up){
  #pragma unroll
  for (int i = 0; i < 4; ++i) cswap(r[i], r[i+4], up);
  #pragma unroll
  for (int b = 0; b < 2; ++b){
    cswap(r[4*b+0], r[4*b+2], up);
    cswap(r[4*b+1], r[4*b+3], up);
  }
  #pragma unroll
  for (int p = 0; p < 4; ++p) cswap(r[2*p], r[2*p+1], up);
}

// ---------------- prep
__global__ __launch_bounds__(256) void k_prep(const float* __restrict__ w_rpe,
        float* __restrict__ qw_sqrt, unsigned* __restrict__ slots_hi,
        unsigned* __restrict__ slots_lo){
  int tid = threadIdx.x;
  if (tid < NSEG){ slots_hi[tid] = 0u; slots_lo[tid] = 0xFFFFFFFFu; }
  __shared__ float S[24][8];
  if (tid < 192){
    int hr = tid >> 3, kk = tid & 7;
    int h = hr / 3, r = hr % 3;
    float s = 0.f;
    #pragma unroll
    for (int d = 0; d < DIM; ++d) s += w_rpe[(h*DIM + d)*24 + (r*8 + kk)];
    S[hr][kk] = expf(fminf(s, 50.f));
  }
  __syncthreads();
  if (tid < 24){
    float q = 0.f;
    #pragma unroll
    for (int kk = 0; kk < 8; ++kk) q += S[tid][kk];
    qw_sqrt[tid] = sqrtf(2.f * q);
  }
}

// ---------------- LN1 + QKV + hash + bf16 hi/lo pre-pack
// One head per block; 256 tokens/block; ONE token per thread (R12 structure).
// Packed row (96 shorts): [0..47] hi of dims 0..47, [48..95] lo.
// Dims 0..31 proj; 32..34 coords; Q: 35=1.0, 36=qsq; K: 35=ksq, 36=1.0; rest 0.
// Two-phase copy-out through a 26 KB STG (128 rows) -> 39 KB LDS -> 4 blocks/CU.
__global__ __launch_bounds__(256, 3) void k_qkv(const float* __restrict__ x,
        const float* __restrict__ n1w, const float* __restrict__ n1b,
        const float* __restrict__ coords, const float* __restrict__ wq,
        const float* __restrict__ wk, const float* __restrict__ wv,
        const float* __restrict__ qw_sqrt, const float* __restrict__ alpha,
        short* __restrict__ qpk, short* __restrict__ kpk, short* __restrict__ vbf,
        float* __restrict__ qh_buf, float* __restrict__ kh_buf,
        unsigned* __restrict__ slots_hi, unsigned* __restrict__ slots_lo){
  __shared__ float W[3][DIM][DIM];    // 12 KB (this head's slices)
  __shared__ float AL[DH][NC];        // 420 B
  __shared__ float LNW[DIM], LNB[DIM];
  __shared__ uint4 STG[1664];         // 26 KB: 128 rows x stride 13
  int h = blockIdx.y;
  int tid = threadIdx.x;
  for (int idx = tid; idx < 3*DIM*DIM; idx += 256){
    int which = idx >> 10, rem = idx & 1023;
    const float* src = which==0 ? wq : (which==1 ? wk : wv);
    W[which][rem>>5][rem&31] = src[(size_t)(rem>>5)*(NH*DIM) + h*DIM + (rem&31)];
  }
  for (int idx = tid; idx < DH*NC; idx += 256) ((float*)AL)[idx] = alpha[h*DH*NC + idx];
  if (tid < DIM) LNW[tid] = n1w[tid];
  else if (tid < 2*DIM) LNB[tid-DIM] = n1b[tid-DIM];
  __syncthreads();

  int base = blockIdx.x * 256;
  int n = base + tid;
  int half = tid >> 7;          // 0: rows base..base+127, 1: base+128..base+255
  int rslot = tid & 127;

  float xa[32];
  {
    const float4* pp = (const float4*)(x + (size_t)n*DIM);
    float4 v[8]; float s = 0.f;
    #pragma unroll
    for (int u = 0; u < 8; ++u){ v[u]=pp[u]; s += v[u].x+v[u].y+v[u].z+v[u].w; }
    float mu = s*(1.f/32.f), var = 0.f;
    #pragma unroll
    for (int u = 0; u < 8; ++u){
      float a0=v[u].x-mu,a1=v[u].y-mu,a2=v[u].z-mu,a3=v[u].w-mu;
      var += a0*a0+a1*a1+a2*a2+a3*a3;
    }
    var *= (1.f/32.f);
    float rs = rsqrtf(var + 1e-5f);
    #pragma unroll
    for (int u = 0; u < 8; ++u){
      xa[u*4+0]=(v[u].x-mu)*rs*LNW[u*4+0]+LNB[u*4+0];
      xa[u*4+1]=(v[u].y-mu)*rs*LNW[u*4+1]+LNB[u*4+1];
      xa[u*4+2]=(v[u].z-mu)*rs*LNW[u*4+2]+LNB[u*4+2];
      xa[u*4+3]=(v[u].w-mu)*rs*LNW[u*4+3]+LNB[u*4+3];
    }
  }

  float c0 = qw_sqrt[h*3+0]*coords[(size_t)n*3+0];
  float c1 = qw_sqrt[h*3+1]*coords[(size_t)n*3+1];
  float c2 = qw_sqrt[h*3+2]*coords[(size_t)n*3+2];
  float csq = c0*c0 + c1*c1 + c2*c2;

  unsigned hiu[16], lou[16];

  // projection into registers (hiu/lou), full 32-dim row per thread
  auto do_proj = [&](int which, float (&hp)[3], float& sq, bool dohash){
    #pragma unroll
    for (int j0 = 0; j0 < 32; j0 += 4){
      float4 a = {0,0,0,0};
      #pragma unroll
      for (int d = 0; d < 32; ++d){
        float4 w4 = *(const float4*)&W[which][d][j0];
        a.x += xa[d]*w4.x; a.y += xa[d]*w4.y; a.z += xa[d]*w4.z; a.w += xa[d]*w4.w;
      }
      if (dohash){
        sq += a.x*a.x; sq += a.y*a.y; sq += a.z*a.z; sq += a.w*a.w;
        #pragma unroll
        for (int c = 0; c < 3; ++c){
          float t = hp[c];
          t += a.x*AL[j0][c];   t += a.y*AL[j0+1][c];
          t += a.z*AL[j0+2][c]; t += a.w*AL[j0+3][c];
          hp[c] = t;
        }
      }
      unsigned short hx=f2bf(a.x),hy=f2bf(a.y),hz=f2bf(a.z),hw=f2bf(a.w);
      hiu[j0/2]   = (unsigned)hx | ((unsigned)hy<<16);
      hiu[j0/2+1] = (unsigned)hz | ((unsigned)hw<<16);
      lou[j0/2]   = (unsigned)f2bf(a.x-bf2f(hx)) | ((unsigned)f2bf(a.y-bf2f(hy))<<16);
      lou[j0/2+1] = (unsigned)f2bf(a.z-bf2f(hz)) | ((unsigned)f2bf(a.w-bf2f(hw))<<16);
    }
  };
  // stage own packed row (12 uint4) into STG slot rslot
  auto stage_row = [&](float x5, float x6){
    uint4* d = &STG[rslot*13];
    uint4 t;
    t.x=hiu[0];  t.y=hiu[1];  t.z=hiu[2];  t.w=hiu[3];  d[0] = t;
    t.x=hiu[4];  t.y=hiu[5];  t.z=hiu[6];  t.w=hiu[7];  d[1] = t;
    t.x=hiu[8];  t.y=hiu[9];  t.z=hiu[10]; t.w=hiu[11]; d[2] = t;
    t.x=hiu[12]; t.y=hiu[13]; t.z=hiu[14]; t.w=hiu[15]; d[3] = t;
    unsigned short h0=f2bf(c0),h1=f2bf(c1),h2=f2bf(c2),h5=f2bf(x5),h6=f2bf(x6);
    uint4 hv;
    hv.x = (unsigned)h0 | ((unsigned)h1<<16);
    hv.y = (unsigned)h2 | ((unsigned)h5<<16);
    hv.z = (unsigned)h6; hv.w = 0;
    d[4] = hv;
    uint4 zz; zz.x=0; zz.y=0; zz.z=0; zz.w=0;
    d[5] = zz;
    t.x=lou[0];  t.y=lou[1];  t.z=lou[2];  t.w=lou[3];  d[6] = t;
    t.x=lou[4];  t.y=lou[5];  t.z=lou[6];  t.w=lou[7];  d[7] = t;
    t.x=lou[8];  t.y=lou[9];  t.z=lou[10]; t.w=lou[11]; d[8] = t;
    t.x=lou[12]; t.y=lou[13]; t.z=lou[14]; t.w=lou[15]; d[9] = t;
    uint4 lv;
    lv.x = (unsigned)f2bf(c0-bf2f(h0)) | ((unsigned)f2bf(c1-bf2f(h1))<<16);
    lv.y = (unsigned)f2bf(c2-bf2f(h2)) | ((unsigned)f2bf(x5-bf2f(h5))<<16);
    lv.z = (unsigned)f2bf(x6-bf2f(h6)); lv.w = 0;
    d[10] = lv;
    d[11] = zz;
  };
  // wave-coalesced copy of 128 staged rows (12 uint4 each) to global
  auto copy_qk = [&](short* gdst){
    uint4* du = (uint4*)gdst;
    #pragma unroll
    for (int it = 0; it < 6; ++it){
      unsigned g = (unsigned)it*256u + (unsigned)tid;   // 1536 total
      unsigned row = g / 12u, k = g % 12u;
      du[g] = STG[row*13u + k];
    }
  };

  float qh[3]={0,0,0}, kh[3]={0,0,0};
  float sq = 0.f;

  // ---- Q (two-phase copy-out)
  do_proj(0, qh, sq, true);
  float qsq = -0.5f*(sq + csq);
  if (half == 0) stage_row(1.0f, qsq);
  __syncthreads();
  copy_qk(qpk + ((size_t)h*NPTS + base)*96);
  __syncthreads();
  if (half == 1) stage_row(1.0f, qsq);
  __syncthreads();
  copy_qk(qpk + ((size_t)h*NPTS + base + 128)*96);
  __syncthreads();

  // ---- K
  sq = 0.f;
  do_proj(1, kh, sq, true);
  float ksq = -0.5f*(sq + csq);
  if (half == 0) stage_row(ksq, 1.0f);
  __syncthreads();
  copy_qk(kpk + ((size_t)h*NPTS + base)*96);
  __syncthreads();
  if (half == 1) stage_row(ksq, 1.0f);
  __syncthreads();
  copy_qk(kpk + ((size_t)h*NPTS + base + 128)*96);
  __syncthreads();

  // ---- V (hi only, 4 uint4/row at stride 5)
  do_proj(2, qh, sq, false);   // qh/sq unused here (dohash=false leaves them)
  auto stage_v = [&](){
    uint4* d = &STG[rslot*5];
    uint4 t;
    t.x=hiu[0];  t.y=hiu[1];  t.z=hiu[2];  t.w=hiu[3];  d[0] = t;
    t.x=hiu[4];  t.y=hiu[5];  t.z=hiu[6];  t.w=hiu[7];  d[1] = t;
    t.x=hiu[8];  t.y=hiu[9];  t.z=hiu[10]; t.w=hiu[11]; d[2] = t;
    t.x=hiu[12]; t.y=hiu[13]; t.z=hiu[14]; t.w=hiu[15]; d[3] = t;
  };
  auto copy_v = [&](short* gdst){
    uint4* dv = (uint4*)gdst;
    #pragma unroll
    for (int it = 0; it < 2; ++it){
      unsigned g = (unsigned)it*256u + (unsigned)tid;   // 512 total
      unsigned row = g >> 2, k = g & 3u;
      dv[g] = STG[row*5u + k];
    }
  };
  if (half == 0) stage_v();
  __syncthreads();
  copy_v(vbf + ((size_t)h*NPTS + base)*32);
  __syncthreads();
  if (half == 1) stage_v();
  __syncthreads();
  copy_v(vbf + ((size_t)h*NPTS + base + 128)*32);

  // hash finalize + min/max
  float mx[3], mn[3];
  #pragma unroll
  for (int c = 0; c < 3; ++c){
    float qt = qh[c];
    qt += c0*AL[32][c]; qt += c1*AL[33][c]; qt += c2*AL[34][c];
    float kt = kh[c];
    kt += c0*AL[32][c]; kt += c1*AL[33][c]; kt += c2*AL[34][c];
    qh_buf[(size_t)(c*NH + h)*NPTS + n] = qt;
    kh_buf[(size_t)(c*NH + h)*NPTS + n] = kt;
    mx[c] = fmaxf(qt, kt);
    mn[c] = fminf(qt, kt);
  }
  #pragma unroll
  for (int c = 0; c < 3; ++c){
    float mx_ = mx[c], mn_ = mn[c];
    #pragma unroll
    for (int off = 1; off <= 32; off <<= 1){
      mx_ = fmaxf(mx_, __shfl_xor(mx_, off));
      mn_ = fminf(mn_, __shfl_xor(mn_, off));
    }
    if ((tid & 63) == 0){
      atomicMax(&slots_hi[c*NH + h], fmap(mx_));
      atomicMin(&slots_lo[c*NH + h], fmap(mn_));
    }
  }
}

// ---------------- pack + bitonic k=2..8192 within 8192-chunk
__global__ __launch_bounds__(1024) void k_sort_pack_local(
        const float* __restrict__ qh_buf, const float* __restrict__ kh_buf,
        const int* __restrict__ shifts,
        const unsigned* __restrict__ slots_hi, const unsigned* __restrict__ slots_lo,
        ull* __restrict__ packed){
  __shared__ ull ld[9216];
  int chunk = blockIdx.x;            // 0..191
  int lst = chunk >> 2;              // 0..47 (0..23 q, 24..47 k)
  int seg = lst < NSEG ? lst : lst - NSEG;
  const float* buf = lst < NSEG ? qh_buf : kh_buf;
  unsigned coff = (unsigned)(chunk & 3) * 8192u;
  float hs = funmap(slots_hi[seg]) - funmap(slots_lo[seg]);
  unsigned tid = threadIdx.x;

  {
    ull r[8];
    unsigned gb = coff + 8u*tid;
    #pragma unroll
    for (int e = 0; e < 8; ++e){
      unsigned n = gb + e;
      size_t gi = (size_t)seg*NPTS + n;
      float key = buf[gi] + (float)shifts[gi] * hs;
      r[e] = ((ull)fmap(key) << 32) | n;
    }
    bitonic8_initial(r, gb);
    #pragma unroll
    for (int e = 0; e < 8; ++e) ld[9u*tid + e] = r[e];
  }
  __syncthreads();

  for (unsigned k = 16; k <= 8192u; k <<= 1){
    for (unsigned j = k >> 1; j >= 8; j >>= 1){
      #pragma unroll
      for (int it = 0; it < 4; ++it){
        unsigned p = tid + 1024u*it;
        unsigned i  = ((p & ~(j-1)) << 1) | (p & (j-1));
        unsigned x2 = i | j;
        bool up = (((coff + i) & k) == 0);
        unsigned pi = i + (i>>3), px = x2 + (x2>>3);
        ull a = ld[pi], b2 = ld[px];
        if ((a > b2) == up){ ld[pi] = b2; ld[px] = a; }
      }
      __syncthreads();
    }
    {
      ull r[8];
      #pragma unroll
      for (int e = 0; e < 8; ++e) r[e] = ld[9u*tid + e];
      bool up = (((coff + 8u*tid) & k) == 0);
      bitonic8_finish(r, up);
      #pragma unroll
      for (int e = 0; e < 8; ++e) ld[9u*tid + e] = r[e];
    }
    __syncthreads();
  }
  size_t base = (size_t)lst*NPTS + coff;
  for (unsigned idx = tid; idx < 8192; idx += 1024)
    packed[base + idx] = ld[idx + (idx>>3)];
}

// ---------------- bitonic: LDS chunk stages
__global__ __launch_bounds__(1024) void k_sort_local(ull* __restrict__ data,
        unsigned k_lo, unsigned k_hi){
  __shared__ ull ld[9216];
  int chunk = blockIdx.x;
  size_t base = (size_t)chunk * 8192;
  unsigned coff = (unsigned)(chunk & 3) * 8192u;
  unsigned tid = threadIdx.x;
  for (unsigned idx = tid; idx < 8192; idx += 1024)
    ld[idx + (idx>>3)] = data[base + idx];
  __syncthreads();
  for (unsigned k = k_lo; k <= k_hi; k <<= 1){
    unsigned j0 = (k >> 1) < 4096u ? (k >> 1) : 4096u;
    for (unsigned j = j0; j >= 8; j >>= 1){
      #pragma unroll
      for (int it = 0; it < 4; ++it){
        unsigned p = tid + 1024u*it;
        unsigned i  = ((p & ~(j-1)) << 1) | (p & (j-1));
        unsigned x2 = i | j;
        bool up = (((coff + i) & k) == 0);
        unsigned pi = i + (i>>3), px = x2 + (x2>>3);
        ull a = ld[pi], b2 = ld[px];
        if ((a > b2) == up){ ld[pi] = b2; ld[px] = a; }
      }
      __syncthreads();
    }
    {
      ull r[8];
      #pragma unroll
      for (int e = 0; e < 8; ++e) r[e] = ld[9u*tid + e];
      bool up = (((coff + 8u*tid) & k) == 0);
      bitonic8_finish(r, up);
      #pragma unroll
      for (int e = 0; e < 8; ++e) ld[9u*tid + e] = r[e];
    }
    __syncthreads();
  }
  for (unsigned idx = tid; idx < 8192; idx += 1024)
    data[base + idx] = ld[idx + (idx>>3)];
}

// ---------------- bitonic sort: one global compare-exchange pass
__global__ __launch_bounds__(256) void k_sort_global(ull* __restrict__ data,
        unsigned k, unsigned j){
  unsigned t = blockIdx.x*256 + threadIdx.x;
  unsigned seg = t >> 14;
  unsigned p = t & 16383u;
  unsigned i  = ((p & ~(j-1)) << 1) | (p & (j-1));
  unsigned x2 = i | j;
  size_t base = (size_t)seg << 15;
  bool up = ((i & k) == 0);
  ull a = data[base + i], b = data[base + x2];
  if ((a > b) == up){ data[base + i] = b; data[base + x2] = a; }
}

// ---------------- fused k=32768 global passes j=16384 and j=8192
__global__ __launch_bounds__(256) void k_sort_global2(ull* __restrict__ data){
  unsigned t = blockIdx.x*256 + threadIdx.x;   // 48*8192 threads
  unsigned seg = t >> 13;
  unsigned i = t & 8191u;
  size_t base = ((size_t)seg << 15) + i;
  ull e0 = data[base], e1 = data[base + 8192], e2 = data[base + 16384], e3 = data[base + 24576];
  cswap(e0, e2, true); cswap(e1, e3, true);   // j = 16384
  cswap(e0, e1, true); cswap(e2, e3, true);   // j = 8192
  data[base] = e0; data[base + 8192] = e1;
  data[base + 16384] = e2; data[base + 24576] = e3;
}

// ---------------- inverse permutation for q side
__global__ __launch_bounds__(256) void k_qrev(const ull* __restrict__ packed,
        unsigned* __restrict__ qrev){
  unsigned t = blockIdx.x*256 + threadIdx.x;   // NSEG*NPTS threads
  unsigned seg = t >> 15;
  unsigned pos = t & 32767u;
  unsigned idx = (unsigned)(packed[(size_t)seg*NPTS + pos] & 0xffffffffull);
  qrev[(size_t)seg*NPTS + idx] = pos;
}

// ---------------- bucketed kernelized attention (copy staging + MFMA,
// sorted-order output: NO atomics)
__global__ __launch_bounds__(512, 8) void k_attn(const short* __restrict__ qpk,
        const short* __restrict__ kpk, const short* __restrict__ vbf,
        const ull* __restrict__ packed, unsigned short* __restrict__ o_sorted,
        float* __restrict__ den_sorted){
  __shared__ short KP[16384];   // 32 KB: K hi rows [128][64] @0, lo @8192; P after barrier
  __shared__ short Vt[4096];    // 8 KB [vdim][key] swizzled

  int t = threadIdx.x;
  int blk = blockIdx.x;
  int seg = blk >> 8;
  int b = blk & 255;
  int h = seg & 7;
  const ull* pq = packed + ((size_t)seg << 15) + (size_t)b*BSZ;
  const ull* pk = packed + ((size_t)(NSEG + seg) << 15) + (size_t)b*BSZ;

  int lane = t & 63;
  int w = t >> 6;
  int l15 = lane & 15, g = lane >> 4;
  int qrow = 16*w + l15;

  // per-lane Q fragments straight from pre-packed global rows
  unsigned iqr = (unsigned)(pq[qrow] & 0xffffffffull);
  const short* qrp = qpk + ((size_t)h*NPTS + iqr)*96;
  bf16x8 qh0 = *(const bf16x8*)&qrp[8*g];
  bf16x8 ql0 = *(const bf16x8*)&qrp[48 + 8*g];
  bf16x8 qh1 = (bf16x8){0,0,0,0,0,0,0,0};
  bf16x8 ql1 = (bf16x8){0,0,0,0,0,0,0,0};
  if (g < 2){
    qh1 = *(const bf16x8*)&qrp[32 + 8*g];
    ql1 = *(const bf16x8*)&qrp[80 + 8*g];
  }

  // staging: row r = t>>2, quarter qd = t&3 — pure 16B copies
  {
    int r = t >> 2;
    int qd = t & 3;
    unsigned ik = (unsigned)(pk[r] & 0xffffffffull);
    int rowbase = r*64;
    int sw = (r & 7) << 3;
    const short* krp = kpk + ((size_t)h*NPTS + ik)*96;
    if (qd < 3){
      bf16x8 h0 = *(const bf16x8*)&krp[16*qd];
      bf16x8 h1 = *(const bf16x8*)&krp[16*qd + 8];
      bf16x8 l0 = *(const bf16x8*)&krp[48 + 16*qd];
      bf16x8 l1 = *(const bf16x8*)&krp[56 + 16*qd];
      *(bf16x8*)&KP[rowbase + ((16*qd) ^ sw)] = h0;
      *(bf16x8*)&KP[rowbase + ((16*qd + 8) ^ sw)] = h1;
      *(bf16x8*)&KP[8192 + rowbase + ((16*qd) ^ sw)] = l0;
      *(bf16x8*)&KP[8192 + rowbase + ((16*qd + 8) ^ sw)] = l1;
    } else {
      bf16x8 z = (bf16x8){0,0,0,0,0,0,0,0};
      *(bf16x8*)&KP[rowbase + (48 ^ sw)] = z;
      *(bf16x8*)&KP[rowbase + (56 ^ sw)] = z;
      *(bf16x8*)&KP[8192 + rowbase + (48 ^ sw)] = z;
      *(bf16x8*)&KP[8192 + rowbase + (56 ^ sw)] = z;
    }
    const short* vrp = vbf + ((size_t)h*NPTS + ik)*32 + 8*qd;
    bf16x8 vv = *(const bf16x8*)vrp;
    #pragma unroll
    for (int d2 = 0; d2 < 8; ++d2){
      int vd = 8*qd + d2;
      Vt[vd*128 + (r ^ ((vd & 7) << 3))] = vv[d2];
    }
  }
  __syncthreads();

  // QK^T: S^T = K.Q^T
  f32x4 acc[8];
  #pragma unroll
  for (int kt = 0; kt < 8; ++kt) acc[kt] = (f32x4){0.f,0.f,0.f,0.f};
  #pragma unroll
  for (int kt = 0; kt < 8; ++kt){
    int krow = 16*kt + l15;
    int base = krow*64;
    int sw = (krow & 7) << 3;
    bf16x8 ah0 = *(const bf16x8*)&KP[base + ((8*g) ^ sw)];
    bf16x8 ah1 = *(const bf16x8*)&KP[base + ((32 + 8*g) ^ sw)];
    bf16x8 al0 = *(const bf16x8*)&KP[8192 + base + ((8*g) ^ sw)];
    bf16x8 al1 = *(const bf16x8*)&KP[8192 + base + ((32 + 8*g) ^ sw)];
    f32x4 c = acc[kt];
    c = __builtin_amdgcn_mfma_f32_16x16x32_bf16(ah0, qh0, c, 0, 0, 0);
    c = __builtin_amdgcn_mfma_f32_16x16x32_bf16(ah1, qh1, c, 0, 0, 0);
    c = __builtin_amdgcn_mfma_f32_16x16x32_bf16(al0, qh0, c, 0, 0, 0);
    c = __builtin_amdgcn_mfma_f32_16x16x32_bf16(al1, qh1, c, 0, 0, 0);
    c = __builtin_amdgcn_mfma_f32_16x16x32_bf16(ah0, ql0, c, 0, 0, 0);
    c = __builtin_amdgcn_mfma_f32_16x16x32_bf16(ah1, ql1, c, 0, 0, 0);
    acc[kt] = c;
  }

  __syncthreads();   // K region dead -> P may overwrite

  // exp + P(bf16 via cvt_pk) into KP as [q=128][key=128]; fp32 denom per lane
  int qsw = (qrow & 7) << 3;
  float dena = 0.f;
  #pragma unroll
  for (int kt = 0; kt < 8; ++kt){
    f32x4 c = acc[kt];
    float p0 = __expf(fminf(c[0], 0.f));
    float p1 = __expf(fminf(c[1], 0.f));
    float p2 = __expf(fminf(c[2], 0.f));
    float p3 = __expf(fminf(c[3], 0.f));
    dena += p0 + p1 + p2 + p3;
    int key = 16*kt + 4*g;
    uint2 pv;
    pv.x = cvtpk_bf16(p0, p1);
    pv.y = cvtpk_bf16(p2, p3);
    *(uint2*)&KP[qrow*128 + (key ^ qsw)] = pv;
  }
  // P write->read within-wave: no barrier

  // PV via MFMA
  f32x4 oacc[2];
  oacc[0] = (f32x4){0.f,0.f,0.f,0.f};
  oacc[1] = (f32x4){0.f,0.f,0.f,0.f};
  #pragma unroll
  for (int ks = 0; ks < 4; ++ks){
    bf16x8 pA = *(const bf16x8*)&KP[qrow*128 + ((32*ks + 8*g) ^ qsw)];
    #pragma unroll
    for (int nt = 0; nt < 2; ++nt){
      int vd = 16*nt + l15;
      bf16x8 vB = *(const bf16x8*)&Vt[vd*128 + ((32*ks + 8*g) ^ ((vd&7)<<3))];
      oacc[nt] = __builtin_amdgcn_mfma_f32_16x16x32_bf16(pA, vB, oacc[nt], 0, 0, 0);
    }
  }

  // denom store (plain, sorted order)
  {
    float d = dena;
    d += __shfl_xor(d, 16);
    d += __shfl_xor(d, 32);
    if (lane < 16) den_sorted[(size_t)seg*NPTS + (size_t)b*BSZ + 16*w + l15] = d;
  }
  // O store (bf16, sorted order, coalesced)
  size_t obase = ((size_t)seg*NPTS + (size_t)b*BSZ)*32;
  #pragma unroll
  for (int nt = 0; nt < 2; ++nt){
    f32x4 c = oacc[nt];
    #pragma unroll
    for (int r = 0; r < 4; ++r){
      int row = 16*w + 4*g + r;
      o_sorted[obase + (size_t)row*32 + 16*nt + l15] = f2bf(c[r]);
    }
  }
}

// ---------------- gather(3 rounds) + out-proj + residual + LN2 + FF + residual
__global__ __launch_bounds__(256) void k_final(const float* __restrict__ x,
        const unsigned short* __restrict__ o_sorted, const float* __restrict__ den_sorted,
        const unsigned* __restrict__ qrev,
        const float* __restrict__ out_w, const float* __restrict__ out_b,
        const float* __restrict__ n2w, const float* __restrict__ n2b,
        const float* __restrict__ f1w, const float* __restrict__ f1b,
        const float* __restrict__ f2w, const float* __restrict__ f2b,
        float* __restrict__ out){
  __shared__ float OW[256][32];   // 32 KB
  __shared__ float F1[32][32];
  __shared__ float F2[32][32];
  int tid = threadIdx.x;
  for (int idx = tid; idx < 256*32; idx += 256) OW[idx/32][idx%32] = out_w[idx];
  for (int idx = tid; idx < 1024; idx += 256){
    F1[idx/32][idx%32] = f1w[idx];
    F2[idx/32][idx%32] = f2w[idx];
  }
  __syncthreads();
  int n = blockIdx.x*256 + tid;
  float attn[32];
  #pragma unroll
  for (int j = 0; j < 32; ++j) attn[j] = out_b[j];
  for (int h = 0; h < 8; ++h){
    float osum[32];
    #pragma unroll
    for (int d = 0; d < 32; ++d) osum[d] = 0.f;
    float den = 3e-20f;
    #pragma unroll
    for (int c = 0; c < 3; ++c){
      size_t sbase = (size_t)(c*NH + h)*NPTS;
      unsigned pp = qrev[sbase + n];
      den += den_sorted[sbase + pp];
      const unsigned short* orow = o_sorted + (sbase + pp)*32;
      #pragma unroll
      for (int u = 0; u < 4; ++u){
        uint4 v = *(const uint4*)&orow[u*8];
        osum[u*8+0] += bf2f((unsigned short)(v.x & 0xffffu));
        osum[u*8+1] += bf2f((unsigned short)(v.x >> 16));
        osum[u*8+2] += bf2f((unsigned short)(v.y & 0xffffu));
        osum[u*8+3] += bf2f((unsigned short)(v.y >> 16));
        osum[u*8+4] += bf2f((unsigned short)(v.z & 0xffffu));
        osum[u*8+5] += bf2f((unsigned short)(v.z >> 16));
        osum[u*8+6] += bf2f((unsigned short)(v.w & 0xffffu));
        osum[u*8+7] += bf2f((unsigned short)(v.w >> 16));
      }
    }
    float inv = 1.f / den;
    #pragma unroll
    for (int d = 0; d < 32; ++d){
      float val = osum[d]*inv;
      const float* wrow = &OW[h*32 + d][0];
      #pragma unroll
      for (int j = 0; j < 32; ++j) attn[j] += val * wrow[j];
    }
  }
  const float* xp = x + (size_t)n*DIM;
  float xr[32]; float s = 0.f;
  #pragma unroll
  for (int d = 0; d < 32; ++d){ xr[d] = xp[d] + attn[d]; s += xr[d]; }
  float mu = s * (1.f/32.f);
  float var = 0.f;
  #pragma unroll
  for (int d = 0; d < 32; ++d){ float dx = xr[d]-mu; var += dx*dx; }
  var *= (1.f/32.f);
  float rs = rsqrtf(var + 1e-5f);
  float xn2[32];
  #pragma unroll
  for (int d = 0; d < 32; ++d) xn2[d] = (xr[d]-mu)*rs*n2w[d] + n2b[d];
  float z[32];
  #pragma unroll
  for (int j = 0; j < 32; ++j) z[j] = f1b[j];
  #pragma unroll
  for (int d = 0; d < 32; ++d){
    float xd = xn2[d];
    const float* wrow = &F1[d][0];
    #pragma unroll
    for (int j = 0; j < 32; ++j) z[j] += xd * wrow[j];
  }
  #pragma unroll
  for (int j = 0; j < 32; ++j) z[j] = z[j] / (1.f + __expf(-z[j]));
  float y[32];
  #pragma unroll
  for (int d = 0; d < 32; ++d) y[d] = f2b[d];
  #pragma unroll
  for (int j = 0; j < 32; ++j){
    float zj = z[j];
    const float* wrow = &F2[j][0];
    #pragma unroll
    for (int d = 0; d < 32; ++d) y[d] += zj * wrow[d];
  }
  float* op = out + (size_t)n*DIM;
  #pragma unroll
  for (int d = 0; d < 32; ++d) op[d] = xr[d] + y[d];
}

extern "C" void kernel_launch(void* const* d_in, const int* in_sizes, int n_in,
                              void* d_out, int out_size, void* d_ws, size_t ws_size,
                              hipStream_t stream){
  const float* x      = (const float*)d_in[0];
  const float* coords = (const float*)d_in[1];
  const int*   shifts = (const int*)d_in[2];
  const float* n1w    = (const float*)d_in[3];
  const float* n1b    = (const float*)d_in[4];
  const float* wq     = (const float*)d_in[5];
  const float* wk     = (const float*)d_in[6];
  const float* wv     = (const float*)d_in[7];
  const float* w_rpe  = (const float*)d_in[8];
  const float* alpha  = (const float*)d_in[9];
  const float* out_w  = (const float*)d_in[10];
  const float* out_b  = (const float*)d_in[11];
  const float* n2w    = (const float*)d_in[12];
  const float* n2b    = (const float*)d_in[13];
  const float* f1w    = (const float*)d_in[14];
  const float* f1b    = (const float*)d_in[15];
  const float* f2w    = (const float*)d_in[16];
  const float* f2b    = (const float*)d_in[17];
  float* out = (float*)d_out;

  char* ws = (char*)d_ws;
  size_t off = 0;
  auto alloc = [&](size_t bytes){ size_t o = off; off += (bytes + 255) & ~(size_t)255; return o; };
  float*    qw_sqrt   = (float*)   (ws + alloc(24*4));
  unsigned* slots_hi  = (unsigned*)(ws + alloc(24*4));
  unsigned* slots_lo  = (unsigned*)(ws + alloc(24*4));
  short*    qpk       = (short*)   (ws + alloc((size_t)NH*NPTS*96*2));
  short*    kpk       = (short*)   (ws + alloc((size_t)NH*NPTS*96*2));
  short*    vbf       = (short*)   (ws + alloc((size_t)NH*NPTS*32*2));
  ull*      packed    = (ull*)     (ws + alloc((size_t)2*NSEG*NPTS*8));
  unsigned short* o_sorted = (unsigned short*)(ws + alloc((size_t)NSEG*NPTS*32*2));
  float*    qh_buf    = (float*)   (ws + alloc((size_t)NSEG*NPTS*4));
  float*    kh_buf    = (float*)   (ws + alloc((size_t)NSEG*NPTS*4));
  if (off > ws_size) return;
  // aliases: qh/kh dead after k_sort_pack_local
  float*    den_sorted = qh_buf;
  unsigned* qrev       = (unsigned*)kh_buf;

  k_prep<<<1, 256, 0, stream>>>(w_rpe, qw_sqrt, slots_hi, slots_lo);
  k_qkv<<<dim3(NPTS/256, NH), 256, 0, stream>>>(x, n1w, n1b, coords, wq, wk, wv,
                                                qw_sqrt, alpha, qpk, kpk, vbf,
                                                qh_buf, kh_buf, slots_hi, slots_lo);
  // 48 segments of 32768 -> bitonic
  k_sort_pack_local<<<2*NSEG*4, 1024, 0, stream>>>(qh_buf, kh_buf, shifts,
                                                   slots_hi, slots_lo, packed);
  k_sort_global<<<(2*NSEG*16384)/256, 256, 0, stream>>>(packed, 16384u, 8192u);
  k_sort_local<<<2*NSEG*4, 1024, 0, stream>>>(packed, 16384u, 16384u);
  k_sort_global2<<<(2*NSEG*8192)/256, 256, 0, stream>>>(packed);
  k_sort_local<<<2*NSEG*4, 1024, 0, stream>>>(packed, 32768u, 32768u);

  k_qrev<<<(NSEG*NPTS)/256, 256, 0, stream>>>(packed, qrev);
  k_attn<<<NSEG*NB, 512, 0, stream>>>(qpk, kpk, vbf, packed, o_sorted, den_sorted);
  k_final<<<NPTS/256, 256, 0, stream>>>(x, o_sorted, den_sorted, qrev, out_w, out_b,
                                        n2w, n2b, f1w, f1b, f2w, f2b, out);
}

// Round 19
// 423.656 us; speedup vs baseline: 1.2392x; 1.2392x over previous
//
#include <hip/hip_runtime.h>

#define NPTS 32768
#define DIM 32
#define NH 8
#define NC 3
#define BSZ 128
#define NB 256
#define DH 35
#define DP 36
#define NSEG 24   // C*H

typedef unsigned long long ull;
typedef __attribute__((ext_vector_type(8))) short bf16x8;
typedef __attribute__((ext_vector_type(4))) float f32x4;

__device__ __forceinline__ unsigned fmap(float f){
  unsigned b = __float_as_uint(f);
  return (b & 0x80000000u) ? ~b : (b | 0x80000000u);
}
__device__ __forceinline__ float funmap(unsigned u){
  unsigned b = (u & 0x80000000u) ? (u & 0x7fffffffu) : ~u;
  return __uint_as_float(b);
}
__device__ __forceinline__ unsigned short f2bf(float f){
  unsigned u = __float_as_uint(f);
  u += 0x7fffu + ((u >> 16) & 1u);
  return (unsigned short)(u >> 16);
}
__device__ __forceinline__ float bf2f(unsigned short h){
  return __uint_as_float(((unsigned)h) << 16);
}
__device__ __forceinline__ unsigned cvtpk_bf16(float a, float b){
  unsigned r;
  asm("v_cvt_pk_bf16_f32 %0, %1, %2" : "=v"(r) : "v"(a), "v"(b));
  return r;
}

__device__ __forceinline__ void cswap(ull& a, ull& b, bool up){
  if ((a > b) == up){ ull t = a; a = b; b = t; }
}
// bitonic stages k=2,4,8 on 8 contiguous elements starting at gbase (gbase%8==0)
__device__ __forceinline__ void bitonic8_initial(ull r[8], unsigned gbase){
  #pragma unroll
  for (int p = 0; p < 4; ++p){
    bool up = (((gbase + 2*p) & 2) == 0);
    cswap(r[2*p], r[2*p+1], up);
  }
  #pragma unroll
  for (int b = 0; b < 2; ++b){
    bool up = (((gbase + 4*b) & 4) == 0);
    cswap(r[4*b+0], r[4*b+2], up);
    cswap(r[4*b+1], r[4*b+3], up);
    cswap(r[4*b+0], r[4*b+1], up);
    cswap(r[4*b+2], r[4*b+3], up);
  }
  bool up = ((gbase & 8) == 0);
  #pragma unroll
  for (int i = 0; i < 4; ++i) cswap(r[i], r[i+4], up);
  #pragma unroll
  for (int b = 0; b < 2; ++b){
    cswap(r[4*b+0], r[4*b+2], up);
    cswap(r[4*b+1], r[4*b+3], up);
  }
  #pragma unroll
  for (int p = 0; p < 4; ++p) cswap(r[2*p], r[2*p+1], up);
}
// j=4,2,1 finish of a stage k>=16; direction uniform across the 8
__device__ __forceinline__ void bitonic8_finish(ull r[8], bool up){
  #pragma unroll
  for (int i = 0; i < 4; ++i) cswap(r[i], r[i+4], up);
  #pragma unroll
  for (int b = 0; b < 2; ++b){
    cswap(r[4*b+0], r[4*b+2], up);
    cswap(r[4*b+1], r[4*b+3], up);
  }
  #pragma unroll
  for (int p = 0; p < 4; ++p) cswap(r[2*p], r[2*p+1], up);
}

// ---------------- prep
__global__ __launch_bounds__(256) void k_prep(const float* __restrict__ w_rpe,
        float* __restrict__ qw_sqrt, unsigned* __restrict__ slots_hi,
        unsigned* __restrict__ slots_lo){
  int tid = threadIdx.x;
  if (tid < NSEG){ slots_hi[tid] = 0u; slots_lo[tid] = 0xFFFFFFFFu; }
  __shared__ float S[24][8];
  if (tid < 192){
    int hr = tid >> 3, kk = tid & 7;
    int h = hr / 3, r = hr % 3;
    float s = 0.f;
    #pragma unroll
    for (int d = 0; d < DIM; ++d) s += w_rpe[(h*DIM + d)*24 + (r*8 + kk)];
    S[hr][kk] = expf(fminf(s, 50.f));
  }
  __syncthreads();
  if (tid < 24){
    float q = 0.f;
    #pragma unroll
    for (int kk = 0; kk < 8; ++kk) q += S[tid][kk];
    qw_sqrt[tid] = sqrtf(2.f * q);
  }
}

// ---------------- LN1 + QKV + hash + bf16 hi/lo pre-pack (one head per block,
// one token per thread; hi/lo conversion streams straight into LDS staging).
// EXACT Round-12 structure (proven clean: WRITE 121 MB, FETCH 5 MB, VGPR 88).
// Packed row (96 shorts): [0..47] hi of dims 0..47, [48..95] lo.
// Dims 0..31 proj; 32..34 coords; Q: 35=1.0, 36=qsq; K: 35=ksq, 36=1.0; rest 0.
__global__ __launch_bounds__(256, 2) void k_qkv(const float* __restrict__ x,
        const float* __restrict__ n1w, const float* __restrict__ n1b,
        const float* __restrict__ coords, const float* __restrict__ wq,
        const float* __restrict__ wk, const float* __restrict__ wv,
        const float* __restrict__ qw_sqrt, const float* __restrict__ alpha,
        short* __restrict__ qpk, short* __restrict__ kpk, short* __restrict__ vbf,
        float* __restrict__ qh_buf, float* __restrict__ kh_buf,
        unsigned* __restrict__ slots_hi, unsigned* __restrict__ slots_lo){
  __shared__ float W[3][DIM][DIM];    // 12 KB (this head's slices)
  __shared__ float AL[DH][NC];        // 420 B
  __shared__ float LNW[DIM], LNB[DIM];
  __shared__ uint4 STG[3328];         // 52 KB staging (256 rows, stride 13)
  int h = blockIdx.y;
  int tid = threadIdx.x;
  for (int idx = tid; idx < 3*DIM*DIM; idx += 256){
    int which = idx >> 10, rem = idx & 1023;
    const float* src = which==0 ? wq : (which==1 ? wk : wv);
    W[which][rem>>5][rem&31] = src[(size_t)(rem>>5)*(NH*DIM) + h*DIM + (rem&31)];
  }
  for (int idx = tid; idx < DH*NC; idx += 256) ((float*)AL)[idx] = alpha[h*DH*NC + idx];
  if (tid < DIM) LNW[tid] = n1w[tid];
  else if (tid < 2*DIM) LNB[tid-DIM] = n1b[tid-DIM];
  __syncthreads();

  int base = blockIdx.x * 256;
  int n = base + tid;

  float xa[32];
  {
    const float4* p = (const float4*)(x + (size_t)n*DIM);
    float4 v[8]; float s = 0.f;
    #pragma unroll
    for (int u = 0; u < 8; ++u){ v[u]=p[u]; s += v[u].x+v[u].y+v[u].z+v[u].w; }
    float mu = s*(1.f/32.f), var = 0.f;
    #pragma unroll
    for (int u = 0; u < 8; ++u){
      float a0=v[u].x-mu,a1=v[u].y-mu,a2=v[u].z-mu,a3=v[u].w-mu;
      var += a0*a0+a1*a1+a2*a2+a3*a3;
    }
    var *= (1.f/32.f);
    float rs = rsqrtf(var + 1e-5f);
    #pragma unroll
    for (int u = 0; u < 8; ++u){
      xa[u*4+0]=(v[u].x-mu)*rs*LNW[u*4+0]+LNB[u*4+0];
      xa[u*4+1]=(v[u].y-mu)*rs*LNW[u*4+1]+LNB[u*4+1];
      xa[u*4+2]=(v[u].z-mu)*rs*LNW[u*4+2]+LNB[u*4+2];
      xa[u*4+3]=(v[u].w-mu)*rs*LNW[u*4+3]+LNB[u*4+3];
    }
  }

  float c0 = qw_sqrt[h*3+0]*coords[(size_t)n*3+0];
  float c1 = qw_sqrt[h*3+1]*coords[(size_t)n*3+1];
  float c2 = qw_sqrt[h*3+2]*coords[(size_t)n*3+2];
  float csq = c0*c0 + c1*c1 + c2*c2;

  // row view: dwords 0..15 hi dims0..31; 16..23 hi tail; 24..39 lo dims0..31; 40..47 lo tail
  uint2* rowp = (uint2*)&STG[tid*13];

  // projection: converts inline to STG; optional hash accumulate
  auto do_proj = [&](int which, float (&hp)[3], float& sq, bool dohash){
    #pragma unroll
    for (int j0 = 0; j0 < 32; j0 += 4){
      float4 a = {0,0,0,0};
      #pragma unroll
      for (int d = 0; d < 32; ++d){
        float4 w4 = *(const float4*)&W[which][d][j0];
        a.x += xa[d]*w4.x; a.y += xa[d]*w4.y; a.z += xa[d]*w4.z; a.w += xa[d]*w4.w;
      }
      if (dohash){
        sq += a.x*a.x; sq += a.y*a.y; sq += a.z*a.z; sq += a.w*a.w;
        #pragma unroll
        for (int c = 0; c < 3; ++c){
          float t = hp[c];
          t += a.x*AL[j0][c];   t += a.y*AL[j0+1][c];
          t += a.z*AL[j0+2][c]; t += a.w*AL[j0+3][c];
          hp[c] = t;
        }
      }
      unsigned short hx=f2bf(a.x),hy=f2bf(a.y),hz=f2bf(a.z),hw=f2bf(a.w);
      uint2 hv, lv;
      hv.x = (unsigned)hx | ((unsigned)hy<<16);
      hv.y = (unsigned)hz | ((unsigned)hw<<16);
      lv.x = (unsigned)f2bf(a.x-bf2f(hx)) | ((unsigned)f2bf(a.y-bf2f(hy))<<16);
      lv.y = (unsigned)f2bf(a.z-bf2f(hz)) | ((unsigned)f2bf(a.w-bf2f(hw))<<16);
      rowp[j0/4] = hv;            // hi dims j0..j0+3
      rowp[12 + j0/4] = lv;       // lo dims j0..j0+3
    }
  };
  auto stage_tail = [&](float x5, float x6){
    unsigned short h0=f2bf(c0),h1=f2bf(c1),h2=f2bf(c2),h5=f2bf(x5),h6=f2bf(x6);
    uint2 z2; z2.x=0; z2.y=0;
    uint2 hv0, hv1, lv0, lv1;
    hv0.x = (unsigned)h0 | ((unsigned)h1<<16);
    hv0.y = (unsigned)h2 | ((unsigned)h5<<16);
    hv1.x = (unsigned)h6; hv1.y = 0;
    lv0.x = (unsigned)f2bf(c0-bf2f(h0)) | ((unsigned)f2bf(c1-bf2f(h1))<<16);
    lv0.y = (unsigned)f2bf(c2-bf2f(h2)) | ((unsigned)f2bf(x5-bf2f(h5))<<16);
    lv1.x = (unsigned)f2bf(x6-bf2f(h6)); lv1.y = 0;
    rowp[8] = hv0; rowp[9] = hv1; rowp[10] = z2; rowp[11] = z2;
    rowp[20] = lv0; rowp[21] = lv1; rowp[22] = z2; rowp[23] = z2;
  };
  // wave-coalesced copy of 256 staged rows (12 uint4 each) to global
  auto copy_qk = [&](short* gdst){
    uint4* du = (uint4*)gdst;
    #pragma unroll
    for (int it = 0; it < 12; ++it){
      unsigned g = (unsigned)it*256u + (unsigned)tid;
      unsigned row = g / 12u, k = g % 12u;
      du[g] = STG[row*13u + k];
    }
  };

  float qh[3]={0,0,0}, kh[3]={0,0,0};
  float sq = 0.f, dum = 0.f;

  // ---- Q
  do_proj(0, qh, sq, true);
  float qsq = -0.5f*(sq + csq);
  stage_tail(1.0f, qsq);
  __syncthreads();
  copy_qk(qpk + ((size_t)h*NPTS + base)*96);
  __syncthreads();

  // ---- K
  sq = 0.f;
  do_proj(1, kh, sq, true);
  float ksq = -0.5f*(sq + csq);
  stage_tail(ksq, 1.0f);
  __syncthreads();
  copy_qk(kpk + ((size_t)h*NPTS + base)*96);
  __syncthreads();

  // ---- V: stage 4 uint4 per row at stride 5 (writes land in dwords 0..15)
  {
    uint2* rv = (uint2*)&STG[tid*5];
    #pragma unroll
    for (int j0 = 0; j0 < 32; j0 += 4){
      float4 a = {0,0,0,0};
      #pragma unroll
      for (int d = 0; d < 32; ++d){
        float4 w4 = *(const float4*)&W[2][d][j0];
        a.x += xa[d]*w4.x; a.y += xa[d]*w4.y; a.z += xa[d]*w4.z; a.w += xa[d]*w4.w;
      }
      uint2 hv;
      hv.x = (unsigned)f2bf(a.x) | ((unsigned)f2bf(a.y)<<16);
      hv.y = (unsigned)f2bf(a.z) | ((unsigned)f2bf(a.w)<<16);
      rv[j0/4] = hv;
    }
  }
  __syncthreads();
  {
    uint4* dv = (uint4*)(vbf + ((size_t)h*NPTS + base)*32);
    #pragma unroll
    for (int it = 0; it < 4; ++it){
      unsigned g = (unsigned)it*256u + (unsigned)tid;
      unsigned row = g >> 2, k = g & 3u;
      dv[g] = STG[row*5u + k];
    }
  }

  // hash finalize + min/max
  float mx[3], mn[3];
  #pragma unroll
  for (int c = 0; c < 3; ++c){
    float qa_ = qh[c];
    qa_ += c0*AL[32][c]; qa_ += c1*AL[33][c]; qa_ += c2*AL[34][c];
    float ka_ = kh[c];
    ka_ += c0*AL[32][c]; ka_ += c1*AL[33][c]; ka_ += c2*AL[34][c];
    qh_buf[(size_t)(c*NH + h)*NPTS + n] = qa_;
    kh_buf[(size_t)(c*NH + h)*NPTS + n] = ka_;
    mx[c] = fmaxf(qa_, ka_);
    mn[c] = fminf(qa_, ka_);
  }
  #pragma unroll
  for (int c = 0; c < 3; ++c){
    float mx_ = mx[c], mn_ = mn[c];
    #pragma unroll
    for (int off = 1; off <= 32; off <<= 1){
      mx_ = fmaxf(mx_, __shfl_xor(mx_, off));
      mn_ = fminf(mn_, __shfl_xor(mn_, off));
    }
    if ((tid & 63) == 0){
      atomicMax(&slots_hi[c*NH + h], fmap(mx_));
      atomicMin(&slots_lo[c*NH + h], fmap(mn_));
    }
  }
  (void)dum;
}

// ---------------- pack + bitonic k=2..8192 within 8192-chunk
__global__ __launch_bounds__(1024) void k_sort_pack_local(
        const float* __restrict__ qh_buf, const float* __restrict__ kh_buf,
        const int* __restrict__ shifts,
        const unsigned* __restrict__ slots_hi, const unsigned* __restrict__ slots_lo,
        ull* __restrict__ packed){
  __shared__ ull ld[9216];
  int chunk = blockIdx.x;            // 0..191
  int lst = chunk >> 2;              // 0..47 (0..23 q, 24..47 k)
  int seg = lst < NSEG ? lst : lst - NSEG;
  const float* buf = lst < NSEG ? qh_buf : kh_buf;
  unsigned coff = (unsigned)(chunk & 3) * 8192u;
  float hs = funmap(slots_hi[seg]) - funmap(slots_lo[seg]);
  unsigned tid = threadIdx.x;

  {
    ull r[8];
    unsigned gb = coff + 8u*tid;
    #pragma unroll
    for (int e = 0; e < 8; ++e){
      unsigned n = gb + e;
      size_t gi = (size_t)seg*NPTS + n;
      float key = buf[gi] + (float)shifts[gi] * hs;
      r[e] = ((ull)fmap(key) << 32) | n;
    }
    bitonic8_initial(r, gb);
    #pragma unroll
    for (int e = 0; e < 8; ++e) ld[9u*tid + e] = r[e];
  }
  __syncthreads();

  for (unsigned k = 16; k <= 8192u; k <<= 1){
    for (unsigned j = k >> 1; j >= 8; j >>= 1){
      #pragma unroll
      for (int it = 0; it < 4; ++it){
        unsigned p = tid + 1024u*it;
        unsigned i  = ((p & ~(j-1)) << 1) | (p & (j-1));
        unsigned x2 = i | j;
        bool up = (((coff + i) & k) == 0);
        unsigned pi = i + (i>>3), px = x2 + (x2>>3);
        ull a = ld[pi], b2 = ld[px];
        if ((a > b2) == up){ ld[pi] = b2; ld[px] = a; }
      }
      __syncthreads();
    }
    {
      ull r[8];
      #pragma unroll
      for (int e = 0; e < 8; ++e) r[e] = ld[9u*tid + e];
      bool up = (((coff + 8u*tid) & k) == 0);
      bitonic8_finish(r, up);
      #pragma unroll
      for (int e = 0; e < 8; ++e) ld[9u*tid + e] = r[e];
    }
    __syncthreads();
  }
  size_t base = (size_t)lst*NPTS + coff;
  for (unsigned idx = tid; idx < 8192; idx += 1024)
    packed[base + idx] = ld[idx + (idx>>3)];
}

// ---------------- bitonic: LDS chunk stages
__global__ __launch_bounds__(1024) void k_sort_local(ull* __restrict__ data,
        unsigned k_lo, unsigned k_hi){
  __shared__ ull ld[9216];
  int chunk = blockIdx.x;
  size_t base = (size_t)chunk * 8192;
  unsigned coff = (unsigned)(chunk & 3) * 8192u;
  unsigned tid = threadIdx.x;
  for (unsigned idx = tid; idx < 8192; idx += 1024)
    ld[idx + (idx>>3)] = data[base + idx];
  __syncthreads();
  for (unsigned k = k_lo; k <= k_hi; k <<= 1){
    unsigned j0 = (k >> 1) < 4096u ? (k >> 1) : 4096u;
    for (unsigned j = j0; j >= 8; j >>= 1){
      #pragma unroll
      for (int it = 0; it < 4; ++it){
        unsigned p = tid + 1024u*it;
        unsigned i  = ((p & ~(j-1)) << 1) | (p & (j-1));
        unsigned x2 = i | j;
        bool up = (((coff + i) & k) == 0);
        unsigned pi = i + (i>>3), px = x2 + (x2>>3);
        ull a = ld[pi], b2 = ld[px];
        if ((a > b2) == up){ ld[pi] = b2; ld[px] = a; }
      }
      __syncthreads();
    }
    {
      ull r[8];
      #pragma unroll
      for (int e = 0; e < 8; ++e) r[e] = ld[9u*tid + e];
      bool up = (((coff + 8u*tid) & k) == 0);
      bitonic8_finish(r, up);
      #pragma unroll
      for (int e = 0; e < 8; ++e) ld[9u*tid + e] = r[e];
    }
    __syncthreads();
  }
  for (unsigned idx = tid; idx < 8192; idx += 1024)
    data[base + idx] = ld[idx + (idx>>3)];
}

// ---------------- bitonic sort: one global compare-exchange pass
__global__ __launch_bounds__(256) void k_sort_global(ull* __restrict__ data,
        unsigned k, unsigned j){
  unsigned t = blockIdx.x*256 + threadIdx.x;
  unsigned seg = t >> 14;
  unsigned p = t & 16383u;
  unsigned i  = ((p & ~(j-1)) << 1) | (p & (j-1));
  unsigned x2 = i | j;
  size_t base = (size_t)seg << 15;
  bool up = ((i & k) == 0);
  ull a = data[base + i], b = data[base + x2];
  if ((a > b) == up){ data[base + i] = b; data[base + x2] = a; }
}

// ---------------- fused k=32768 global passes j=16384 and j=8192
__global__ __launch_bounds__(256) void k_sort_global2(ull* __restrict__ data){
  unsigned t = blockIdx.x*256 + threadIdx.x;   // 48*8192 threads
  unsigned seg = t >> 13;
  unsigned i = t & 8191u;
  size_t base = ((size_t)seg << 15) + i;
  ull e0 = data[base], e1 = data[base + 8192], e2 = data[base + 16384], e3 = data[base + 24576];
  cswap(e0, e2, true); cswap(e1, e3, true);   // j = 16384
  cswap(e0, e1, true); cswap(e2, e3, true);   // j = 8192
  data[base] = e0; data[base + 8192] = e1;
  data[base + 16384] = e2; data[base + 24576] = e3;
}

// ---------------- inverse permutation for q side
__global__ __launch_bounds__(256) void k_qrev(const ull* __restrict__ packed,
        unsigned* __restrict__ qrev){
  unsigned t = blockIdx.x*256 + threadIdx.x;   // NSEG*NPTS threads
  unsigned seg = t >> 15;
  unsigned pos = t & 32767u;
  unsigned idx = (unsigned)(packed[(size_t)seg*NPTS + pos] & 0xffffffffull);
  qrev[(size_t)seg*NPTS + idx] = pos;
}

// ---------------- bucketed kernelized attention (copy staging + MFMA,
// sorted-order output: NO atomics)
__global__ __launch_bounds__(512, 8) void k_attn(const short* __restrict__ qpk,
        const short* __restrict__ kpk, const short* __restrict__ vbf,
        const ull* __restrict__ packed, unsigned short* __restrict__ o_sorted,
        float* __restrict__ den_sorted){
  __shared__ short KP[16384];   // 32 KB: K hi rows [128][64] @0, lo @8192; P after barrier
  __shared__ short Vt[4096];    // 8 KB [vdim][key] swizzled

  int t = threadIdx.x;
  int blk = blockIdx.x;
  int seg = blk >> 8;
  int b = blk & 255;
  int h = seg & 7;
  const ull* pq = packed + ((size_t)seg << 15) + (size_t)b*BSZ;
  const ull* pk = packed + ((size_t)(NSEG + seg) << 15) + (size_t)b*BSZ;

  int lane = t & 63;
  int w = t >> 6;
  int l15 = lane & 15, g = lane >> 4;
  int qrow = 16*w + l15;

  // per-lane Q fragments straight from pre-packed global rows
  unsigned iqr = (unsigned)(pq[qrow] & 0xffffffffull);
  const short* qrp = qpk + ((size_t)h*NPTS + iqr)*96;
  bf16x8 qh0 = *(const bf16x8*)&qrp[8*g];
  bf16x8 ql0 = *(const bf16x8*)&qrp[48 + 8*g];
  bf16x8 qh1 = (bf16x8){0,0,0,0,0,0,0,0};
  bf16x8 ql1 = (bf16x8){0,0,0,0,0,0,0,0};
  if (g < 2){
    qh1 = *(const bf16x8*)&qrp[32 + 8*g];
    ql1 = *(const bf16x8*)&qrp[80 + 8*g];
  }

  // staging: row r = t>>2, quarter qd = t&3 — pure 16B copies
  {
    int r = t >> 2;
    int qd = t & 3;
    unsigned ik = (unsigned)(pk[r] & 0xffffffffull);
    int rowbase = r*64;
    int sw = (r & 7) << 3;
    const short* krp = kpk + ((size_t)h*NPTS + ik)*96;
    if (qd < 3){
      bf16x8 h0 = *(const bf16x8*)&krp[16*qd];
      bf16x8 h1 = *(const bf16x8*)&krp[16*qd + 8];
      bf16x8 l0 = *(const bf16x8*)&krp[48 + 16*qd];
      bf16x8 l1 = *(const bf16x8*)&krp[56 + 16*qd];
      *(bf16x8*)&KP[rowbase + ((16*qd) ^ sw)] = h0;
      *(bf16x8*)&KP[rowbase + ((16*qd + 8) ^ sw)] = h1;
      *(bf16x8*)&KP[8192 + rowbase + ((16*qd) ^ sw)] = l0;
      *(bf16x8*)&KP[8192 + rowbase + ((16*qd + 8) ^ sw)] = l1;
    } else {
      bf16x8 z = (bf16x8){0,0,0,0,0,0,0,0};
      *(bf16x8*)&KP[rowbase + (48 ^ sw)] = z;
      *(bf16x8*)&KP[rowbase + (56 ^ sw)] = z;
      *(bf16x8*)&KP[8192 + rowbase + (48 ^ sw)] = z;
      *(bf16x8*)&KP[8192 + rowbase + (56 ^ sw)] = z;
    }
    const short* vrp = vbf + ((size_t)h*NPTS + ik)*32 + 8*qd;
    bf16x8 vv = *(const bf16x8*)vrp;
    #pragma unroll
    for (int d2 = 0; d2 < 8; ++d2){
      int vd = 8*qd + d2;
      Vt[vd*128 + (r ^ ((vd & 7) << 3))] = vv[d2];
    }
  }
  __syncthreads();

  // QK^T: S^T = K.Q^T
  f32x4 acc[8];
  #pragma unroll
  for (int kt = 0; kt < 8; ++kt) acc[kt] = (f32x4){0.f,0.f,0.f,0.f};
  #pragma unroll
  for (int kt = 0; kt < 8; ++kt){
    int krow = 16*kt + l15;
    int base = krow*64;
    int sw = (krow & 7) << 3;
    bf16x8 ah0 = *(const bf16x8*)&KP[base + ((8*g) ^ sw)];
    bf16x8 ah1 = *(const bf16x8*)&KP[base + ((32 + 8*g) ^ sw)];
    bf16x8 al0 = *(const bf16x8*)&KP[8192 + base + ((8*g) ^ sw)];
    bf16x8 al1 = *(const bf16x8*)&KP[8192 + base + ((32 + 8*g) ^ sw)];
    f32x4 c = acc[kt];
    c = __builtin_amdgcn_mfma_f32_16x16x32_bf16(ah0, qh0, c, 0, 0, 0);
    c = __builtin_amdgcn_mfma_f32_16x16x32_bf16(ah1, qh1, c, 0, 0, 0);
    c = __builtin_amdgcn_mfma_f32_16x16x32_bf16(al0, qh0, c, 0, 0, 0);
    c = __builtin_amdgcn_mfma_f32_16x16x32_bf16(al1, qh1, c, 0, 0, 0);
    c = __builtin_amdgcn_mfma_f32_16x16x32_bf16(ah0, ql0, c, 0, 0, 0);
    c = __builtin_amdgcn_mfma_f32_16x16x32_bf16(ah1, ql1, c, 0, 0, 0);
    acc[kt] = c;
  }

  __syncthreads();   // K region dead -> P may overwrite

  // exp + P(bf16 via cvt_pk) into KP as [q=128][key=128]; fp32 denom per lane
  int qsw = (qrow & 7) << 3;
  float dena = 0.f;
  #pragma unroll
  for (int kt = 0; kt < 8; ++kt){
    f32x4 c = acc[kt];
    float p0 = __expf(fminf(c[0], 0.f));
    float p1 = __expf(fminf(c[1], 0.f));
    float p2 = __expf(fminf(c[2], 0.f));
    float p3 = __expf(fminf(c[3], 0.f));
    dena += p0 + p1 + p2 + p3;
    int key = 16*kt + 4*g;
    uint2 pv;
    pv.x = cvtpk_bf16(p0, p1);
    pv.y = cvtpk_bf16(p2, p3);
    *(uint2*)&KP[qrow*128 + (key ^ qsw)] = pv;
  }
  // P write->read within-wave: no barrier

  // PV via MFMA
  f32x4 oacc[2];
  oacc[0] = (f32x4){0.f,0.f,0.f,0.f};
  oacc[1] = (f32x4){0.f,0.f,0.f,0.f};
  #pragma unroll
  for (int ks = 0; ks < 4; ++ks){
    bf16x8 pA = *(const bf16x8*)&KP[qrow*128 + ((32*ks + 8*g) ^ qsw)];
    #pragma unroll
    for (int nt = 0; nt < 2; ++nt){
      int vd = 16*nt + l15;
      bf16x8 vB = *(const bf16x8*)&Vt[vd*128 + ((32*ks + 8*g) ^ ((vd&7)<<3))];
      oacc[nt] = __builtin_amdgcn_mfma_f32_16x16x32_bf16(pA, vB, oacc[nt], 0, 0, 0);
    }
  }

  // denom store (plain, sorted order)
  {
    float d = dena;
    d += __shfl_xor(d, 16);
    d += __shfl_xor(d, 32);
    if (lane < 16) den_sorted[(size_t)seg*NPTS + (size_t)b*BSZ + 16*w + l15] = d;
  }
  // O store (bf16, sorted order, coalesced)
  size_t obase = ((size_t)seg*NPTS + (size_t)b*BSZ)*32;
  #pragma unroll
  for (int nt = 0; nt < 2; ++nt){
    f32x4 c = oacc[nt];
    #pragma unroll
    for (int r = 0; r < 4; ++r){
      int row = 16*w + 4*g + r;
      o_sorted[obase + (size_t)row*32 + 16*nt + l15] = f2bf(c[r]);
    }
  }
}

// ---------------- gather(3 rounds) + out-proj + residual + LN2 + FF + residual
__global__ __launch_bounds__(256) void k_final(const float* __restrict__ x,
        const unsigned short* __restrict__ o_sorted, const float* __restrict__ den_sorted,
        const unsigned* __restrict__ qrev,
        const float* __restrict__ out_w, const float* __restrict__ out_b,
        const float* __restrict__ n2w, const float* __restrict__ n2b,
        const float* __restrict__ f1w, const float* __restrict__ f1b,
        const float* __restrict__ f2w, const float* __restrict__ f2b,
        float* __restrict__ out){
  __shared__ float OW[256][32];   // 32 KB
  __shared__ float F1[32][32];
  __shared__ float F2[32][32];
  int tid = threadIdx.x;
  for (int idx = tid; idx < 256*32; idx += 256) OW[idx/32][idx%32] = out_w[idx];
  for (int idx = tid; idx < 1024; idx += 256){
    F1[idx/32][idx%32] = f1w[idx];
    F2[idx/32][idx%32] = f2w[idx];
  }
  __syncthreads();
  int n = blockIdx.x*256 + tid;
  float attn[32];
  #pragma unroll
  for (int j = 0; j < 32; ++j) attn[j] = out_b[j];
  for (int h = 0; h < 8; ++h){
    float osum[32];
    #pragma unroll
    for (int d = 0; d < 32; ++d) osum[d] = 0.f;
    float den = 3e-20f;
    #pragma unroll
    for (int c = 0; c < 3; ++c){
      size_t sbase = (size_t)(c*NH + h)*NPTS;
      unsigned pp = qrev[sbase + n];
      den += den_sorted[sbase + pp];
      const unsigned short* orow = o_sorted + (sbase + pp)*32;
      #pragma unroll
      for (int u = 0; u < 4; ++u){
        uint4 v = *(const uint4*)&orow[u*8];
        osum[u*8+0] += bf2f((unsigned short)(v.x & 0xffffu));
        osum[u*8+1] += bf2f((unsigned short)(v.x >> 16));
        osum[u*8+2] += bf2f((unsigned short)(v.y & 0xffffu));
        osum[u*8+3] += bf2f((unsigned short)(v.y >> 16));
        osum[u*8+4] += bf2f((unsigned short)(v.z & 0xffffu));
        osum[u*8+5] += bf2f((unsigned short)(v.z >> 16));
        osum[u*8+6] += bf2f((unsigned short)(v.w & 0xffffu));
        osum[u*8+7] += bf2f((unsigned short)(v.w >> 16));
      }
    }
    float inv = 1.f / den;
    #pragma unroll
    for (int d = 0; d < 32; ++d){
      float val = osum[d]*inv;
      const float* wrow = &OW[h*32 + d][0];
      #pragma unroll
      for (int j = 0; j < 32; ++j) attn[j] += val * wrow[j];
    }
  }
  const float* xp = x + (size_t)n*DIM;
  float xr[32]; float s = 0.f;
  #pragma unroll
  for (int d = 0; d < 32; ++d){ xr[d] = xp[d] + attn[d]; s += xr[d]; }
  float mu = s * (1.f/32.f);
  float var = 0.f;
  #pragma unroll
  for (int d = 0; d < 32; ++d){ float dx = xr[d]-mu; var += dx*dx; }
  var *= (1.f/32.f);
  float rs = rsqrtf(var + 1e-5f);
  float xn2[32];
  #pragma unroll
  for (int d = 0; d < 32; ++d) xn2[d] = (xr[d]-mu)*rs*n2w[d] + n2b[d];
  float z[32];
  #pragma unroll
  for (int j = 0; j < 32; ++j) z[j] = f1b[j];
  #pragma unroll
  for (int d = 0; d < 32; ++d){
    float xd = xn2[d];
    const float* wrow = &F1[d][0];
    #pragma unroll
    for (int j = 0; j < 32; ++j) z[j] += xd * wrow[j];
  }
  #pragma unroll
  for (int j = 0; j < 32; ++j) z[j] = z[j] / (1.f + __expf(-z[j]));
  float y[32];
  #pragma unroll
  for (int d = 0; d < 32; ++d) y[d] = f2b[d];
  #pragma unroll
  for (int j = 0; j < 32; ++j){
    float zj = z[j];
    const float* wrow = &F2[j][0];
    #pragma unroll
    for (int d = 0; d < 32; ++d) y[d] += zj * wrow[d];
  }
  float* op = out + (size_t)n*DIM;
  #pragma unroll
  for (int d = 0; d < 32; ++d) op[d] = xr[d] + y[d];
}

extern "C" void kernel_launch(void* const* d_in, const int* in_sizes, int n_in,
                              void* d_out, int out_size, void* d_ws, size_t ws_size,
                              hipStream_t stream){
  const float* x      = (const float*)d_in[0];
  const float* coords = (const float*)d_in[1];
  const int*   shifts = (const int*)d_in[2];
  const float* n1w    = (const float*)d_in[3];
  const float* n1b    = (const float*)d_in[4];
  const float* wq     = (const float*)d_in[5];
  const float* wk     = (const float*)d_in[6];
  const float* wv     = (const float*)d_in[7];
  const float* w_rpe  = (const float*)d_in[8];
  const float* alpha  = (const float*)d_in[9];
  const float* out_w  = (const float*)d_in[10];
  const float* out_b  = (const float*)d_in[11];
  const float* n2w    = (const float*)d_in[12];
  const float* n2b    = (const float*)d_in[13];
  const float* f1w    = (const float*)d_in[14];
  const float* f1b    = (const float*)d_in[15];
  const float* f2w    = (const float*)d_in[16];
  const float* f2b    = (const float*)d_in[17];
  float* out = (float*)d_out;

  char* ws = (char*)d_ws;
  size_t off = 0;
  auto alloc = [&](size_t bytes){ size_t o = off; off += (bytes + 255) & ~(size_t)255; return o; };
  float*    qw_sqrt   = (float*)   (ws + alloc(24*4));
  unsigned* slots_hi  = (unsigned*)(ws + alloc(24*4));
  unsigned* slots_lo  = (unsigned*)(ws + alloc(24*4));
  short*    qpk       = (short*)   (ws + alloc((size_t)NH*NPTS*96*2));
  short*    kpk       = (short*)   (ws + alloc((size_t)NH*NPTS*96*2));
  short*    vbf       = (short*)   (ws + alloc((size_t)NH*NPTS*32*2));
  ull*      packed    = (ull*)     (ws + alloc((size_t)2*NSEG*NPTS*8));
  unsigned short* o_sorted = (unsigned short*)(ws + alloc((size_t)NSEG*NPTS*32*2));
  float*    qh_buf    = (float*)   (ws + alloc((size_t)NSEG*NPTS*4));
  float*    kh_buf    = (float*)   (ws + alloc((size_t)NSEG*NPTS*4));
  if (off > ws_size) return;
  // aliases: qh/kh dead after k_sort_pack_local
  float*    den_sorted = qh_buf;
  unsigned* qrev       = (unsigned*)kh_buf;

  k_prep<<<1, 256, 0, stream>>>(w_rpe, qw_sqrt, slots_hi, slots_lo);
  k_qkv<<<dim3(NPTS/256, NH), 256, 0, stream>>>(x, n1w, n1b, coords, wq, wk, wv,
                                                qw_sqrt, alpha, qpk, kpk, vbf,
                                                qh_buf, kh_buf, slots_hi, slots_lo);
  // 48 segments of 32768 -> bitonic
  k_sort_pack_local<<<2*NSEG*4, 1024, 0, stream>>>(qh_buf, kh_buf, shifts,
                                                   slots_hi, slots_lo, packed);
  k_sort_global<<<(2*NSEG*16384)/256, 256, 0, stream>>>(packed, 16384u, 8192u);
  k_sort_local<<<2*NSEG*4, 1024, 0, stream>>>(packed, 16384u, 16384u);
  k_sort_global2<<<(2*NSEG*8192)/256, 256, 0, stream>>>(packed);
  k_sort_local<<<2*NSEG*4, 1024, 0, stream>>>(packed, 32768u, 32768u);

  k_qrev<<<(NSEG*NPTS)/256, 256, 0, stream>>>(packed, qrev);
  k_attn<<<NSEG*NB, 512, 0, stream>>>(qpk, kpk, vbf, packed, o_sorted, den_sorted);
  k_final<<<NPTS/256, 256, 0, stream>>>(x, o_sorted, den_sorted, qrev, out_w, out_b,
                                        n2w, n2b, f1w, f1b, f2w, f2b, out);
}